// Round 11
// baseline (142.839 us; speedup 1.0000x reference)
//
#include <hip/hip_runtime.h>
#include <math.h>

#define TPB 256
#define TPBS 1024    // select block size
#define LDSF 12288   // select LDS stage capacity in floats (48 KB)

typedef unsigned long long ull;
typedef float pf4 __attribute__((ext_vector_type(4), aligned(4)));  // 4B-aligned float4

__device__ __forceinline__ float jac(float tx0, float ty0, float tx1, float ty1, float ta,
                                     float px0, float py0, float px1, float py1, float pa) {
    float ltx = fmaxf(tx0, px0), lty = fmaxf(ty0, py0);
    float rbx = fminf(tx1, px1), rby = fminf(ty1, py1);
    float w = fmaxf(rbx - ltx, 0.0f), h = fmaxf(rby - lty, 0.0f);
    float inter = w * h;
    return inter / (ta + pa - inter);
}

// ONE pass over all priors (grid B*CB2, thread-per-prior), producing:
//  - per-chunk per-o best-prior key partials (match1 folded in: jac computed
//    ONCE for both the per-o argmax and the per-p sweep)
//  - TENTATIVE mined / smooth-L1 / positive sums (no forced-match override —
//    that touches <= O priors per batch; fixed up in select, proven bit-exact
//    in R9: absmax 0.0)
// Key = (ov_bits<<32) | (0xFFFFFFFF - p): ov >= 0 -> bit-monotone; ~p gives
// first-max (smallest p) on ties, matching the reference argmax over P.
template <int ON, int CN>
__global__ __launch_bounds__(TPB) void fused_kernel(
    const float* __restrict__ loc, const float* __restrict__ priors,
    const float* __restrict__ targets, const float* __restrict__ conf,
    int P, int O_rt, int C_rt, int CB2,
    float* __restrict__ mined, ull* __restrict__ pkeys,
    float* __restrict__ part_ll, float* __restrict__ part_pc,
    int* __restrict__ part_np, int* __restrict__ counter) {
    constexpr int OMAX = (ON > 0) ? ON : 64;
    constexpr int CC = (CN > 0) ? CN : 32;
    const int O = (ON > 0) ? ON : O_rt;
    const int C = (CN > 0) ? CN : C_rt;
    const int b = blockIdx.x / CB2;
    const int chunk = blockIdx.x % CB2;
    const int tid = threadIdx.x;
    const int p = chunk * TPB + tid;
    const bool pv = (p < P);
    const int lane = tid & 63, wv = tid >> 6;

    if (blockIdx.x == 0 && tid == 0) *counter = 0;  // for select's last-block finalize

    __shared__ float s_tx0[OMAX], s_ty0[OMAX], s_tx1[OMAX], s_ty1[OMAX];
    __shared__ float s_lab[OMAX], s_area[OMAX];
    __shared__ ull s_wk[TPB / 64][OMAX];
    __shared__ float s_wll[TPB / 64], s_wpc[TPB / 64];
    __shared__ int s_wnp[TPB / 64];

    // ---- issue conf-row + prior loads FIRST (latency overlaps setup) ----
    float rv[CC];
    float4 pr4 = make_float4(0.f, 0.f, 1.f, 1.f);
    if (pv) {
        const float* row = conf + ((size_t)b * P + p) * C;
        if (CN > 0) {
#pragma unroll
            for (int q = 0; q < CN / 4; ++q) {
                pf4 v = *(const pf4*)(row + 4 * q);
#pragma unroll
                for (int e = 0; e < 4; ++e) rv[4 * q + e] = v[e];
            }
#pragma unroll
            for (int j = (CN / 4) * 4; j < CN; ++j) rv[j] = row[j];
        } else {
            for (int j = 0; j < C; ++j) rv[j] = row[j];
        }
        pr4 = ((const float4*)priors)[p];
    }

    for (int o = tid; o < O; o += TPB) {
        const float* t = targets + ((size_t)b * O + o) * 5;
        float x0 = t[0], y0 = t[1], x1 = t[2], y1 = t[3];
        s_tx0[o] = x0; s_ty0[o] = y0; s_tx1[o] = x1; s_ty1[o] = y1;
        s_lab[o] = t[4];
        s_area[o] = (x1 - x0) * (y1 - y0);
    }
    __syncthreads();

    // ---- jac sweep: tentative per-p best (first-max over o) AND per-o
    //      wave-reduced argmax key (reduced inline, register-light) ----
    float cx = pr4.x, cy = pr4.y, pw = pr4.z, ph = pr4.w;
    float px0 = cx - pw * 0.5f, py0 = cy - ph * 0.5f;
    float px1 = cx + pw * 0.5f, py1 = cy + ph * 0.5f;
    float pa = (px1 - px0) * (py1 - py0);
    float bto = -1.0f;
    int bti = 0;
    for (int o = 0; o < O; ++o) {
        ull kk = 0ull;
        if (pv) {
            float ov = jac(s_tx0[o], s_ty0[o], s_tx1[o], s_ty1[o], s_area[o],
                           px0, py0, px1, py1, pa);
            kk = ((ull)__float_as_uint(ov) << 32) |
                 (ull)(0xFFFFFFFFu - (unsigned)p);
            if (ov > bto) { bto = ov; bti = o; }  // strictly > keeps earliest o
        }
#pragma unroll
        for (int d = 1; d < 64; d <<= 1) {
            ull other = __shfl_xor(kk, d, 64);
            if (other > kk) kk = other;
        }
        if (lane == 0) s_wk[wv][o] = kk;
    }
    __syncthreads();
    if (tid < O) {
        ull kk = s_wk[0][tid];
        for (int w = 1; w < TPB / 64; ++w)
            if (s_wk[w][tid] > kk) kk = s_wk[w][tid];
        pkeys[((size_t)b * O + tid) * CB2 + chunk] = kk;
    }

    // ---- tentative conf loss + smooth-L1 (no forced override) ----
    float ll = 0.0f, pc = 0.0f;
    int np = 0;
    if (pv) {
        float m = rv[0];
#pragma unroll
        for (int j = 1; j < CC; ++j) { if (CN > 0 || j < C) m = fmaxf(m, rv[j]); }
        float s = 0.0f;
#pragma unroll
        for (int j = 0; j < CC; ++j) { if (CN > 0 || j < C) s += expf(rv[j] - m); }
        float lse = m + logf(s);

        int c = (bto < 0.5f) ? 0 : ((int)s_lab[bti] + 1);
        float rowc = rv[0];
#pragma unroll
        for (int j = 1; j < CC; ++j) { if (CN > 0 || j < C) { if (c == j) rowc = rv[j]; } }
        float lc = lse - rowc;  // >= 0 always (s >= 1)

        bool pos = c > 0;
        mined[(size_t)b * P + p] = pos ? 0.0f : lc;
        if (pos) {
            pc = lc;
            np = 1;
            float mx0 = s_tx0[bti], my0 = s_ty0[bti];
            float mx1 = s_tx1[bti], my1 = s_ty1[bti];
            float g0 = ((mx0 + mx1) * 0.5f - cx) / (0.1f * pw);
            float g1 = ((my0 + my1) * 0.5f - cy) / (0.1f * ph);
            float g2 = logf(fmaxf((mx1 - mx0) / pw, 1e-8f)) / 0.2f;
            float g3 = logf(fmaxf((my1 - my0) / ph, 1e-8f)) / 0.2f;
            float4 ld = ((const float4*)loc)[(size_t)b * P + p];
            float gt4[4] = {g0, g1, g2, g3};
            float lv[4] = {ld.x, ld.y, ld.z, ld.w};
#pragma unroll
            for (int q = 0; q < 4; ++q) {
                float d = lv[q] - gt4[q];
                float ad = fabsf(d);
                ll += (ad < 1.0f) ? 0.5f * d * d : (ad - 0.5f);
            }
        }
    }

#pragma unroll
    for (int d = 1; d < 64; d <<= 1) {
        ll += __shfl_xor(ll, d, 64);
        pc += __shfl_xor(pc, d, 64);
        np += __shfl_xor(np, d, 64);
    }
    if (lane == 0) { s_wll[wv] = ll; s_wpc[wv] = pc; s_wnp[wv] = np; }
    __syncthreads();
    if (tid == 0) {
        float L = 0.f, Pc = 0.f;
        int N = 0;
        for (int w = 0; w < TPB / 64; ++w) { L += s_wll[w]; Pc += s_wpc[w]; N += s_wnp[w]; }
        part_ll[blockIdx.x] = L;
        part_pc[blockIdx.x] = Pc;
        part_np[blockIdx.x] = N;
    }
}

// One 1024-thread block per batch (LDS-staged, R10 structure + R9 fixup):
//  1. stage mined row into static LDS (coalesced; NOT scratch — R9's lesson)
//  2. reduce per-chunk argmax keys -> bp[o]; zero forced priors in s_m
//  3. FIXUP (one wave, <= O priors; dedup: largest o owns p = last-wins
//     scatter): recompute tentative contribution with bit-identical op order
//     and apply delta(ll, pos-conf, npos)   [proven absmax 0.0 in R9]
//  4. radix-select k-th largest (values >= 0, bit-monotone); per-wave LDS
//     histograms + intra-wave shuffle suffix scan;
//     sum(top-k) = sum_{>T} + (k-cnt_gt)*T — exact under ties
//  5. last-block-done finalize (threadfence + device atomic counter)
template <int ON, int CN>
__global__ __launch_bounds__(TPBS) void select_kernel(
    const float* __restrict__ mined, const float* __restrict__ conf,
    const float* __restrict__ loc, const float* __restrict__ priors,
    const float* __restrict__ targets, const ull* __restrict__ pkeys,
    const float* __restrict__ part_ll, const float* __restrict__ part_pc,
    const int* __restrict__ part_np,
    float* __restrict__ ll_batch, float* __restrict__ lc_batch,
    int* __restrict__ np_batch,
    int P, int O_rt, int C_rt, int CB2, int ratio, int B,
    int* __restrict__ counter, float* __restrict__ out) {
    constexpr int OMAX = (ON > 0) ? ON : 64;
    const int O = (ON > 0) ? ON : O_rt;
    const int C = (CN > 0) ? CN : C_rt;
    const int b = blockIdx.x, tid = threadIdx.x;
    const int lane = tid & 63, wv = tid >> 6;
    constexpr int W = TPBS / 64;  // 16 waves
    const float* v = mined + (size_t)b * P;
    const bool lds = (P <= LDSF);

    __shared__ float s_m[LDSF];       // 48 KB staged row
    __shared__ int s_hist[W * 256];   // 16 KB per-wave histograms
    __shared__ float s_tx0[OMAX], s_ty0[OMAX], s_tx1[OMAX], s_ty1[OMAX];
    __shared__ float s_lab[OMAX], s_area[OMAX];
    __shared__ ull s_keys[OMAX];
    __shared__ int s_bp[OMAX];
    __shared__ float s_wf[W], s_wg[W];
    __shared__ int s_wi[W];
    __shared__ int s_wt[4];
    __shared__ unsigned s_bsel;
    __shared__ int s_krn;
    __shared__ float s_bc[2], s_fix[2];
    __shared__ int s_bn, s_fixn, s_last;

    // 1. stage mined row; overlap: per-chunk tentative partial reduction
    if (lds) {
        for (int i = tid; i < P; i += TPBS) s_m[i] = v[i];
    }
    float pll = 0.0f, ppc = 0.0f;
    int pnp = 0;
    for (int i = tid; i < CB2; i += TPBS) {
        pll += part_ll[b * CB2 + i];
        ppc += part_pc[b * CB2 + i];
        pnp += part_np[b * CB2 + i];
    }
#pragma unroll
    for (int d = 1; d < 64; d <<= 1) {
        pll += __shfl_xor(pll, d, 64);
        ppc += __shfl_xor(ppc, d, 64);
        pnp += __shfl_xor(pnp, d, 64);
    }
    if (lane == 0) { s_wf[wv] = pll; s_wg[wv] = ppc; s_wi[wv] = pnp; }

    if (tid < O) {
        const float* t = targets + ((size_t)b * O + tid) * 5;
        float x0 = t[0], y0 = t[1], x1 = t[2], y1 = t[3];
        s_tx0[tid] = x0; s_ty0[tid] = y0; s_tx1[tid] = x1; s_ty1[tid] = y1;
        s_lab[tid] = t[4];
        s_area[tid] = (x1 - x0) * (y1 - y0);
        s_keys[tid] = 0ull;
    }
    __syncthreads();

    // 2. reduce per-chunk keys (block-local LDS atomics, O*CB2 entries)
    for (int i = tid; i < O * CB2; i += TPBS) {
        int o = i / CB2, s = i % CB2;
        atomicMax(&s_keys[o], pkeys[((size_t)b * O + o) * CB2 + s]);
    }
    __syncthreads();
    if (tid < O)
        s_bp[tid] = (int)(0xFFFFFFFFu - (unsigned)(s_keys[tid] & 0xFFFFFFFFull));
    __syncthreads();

    // zero forced priors in the staged row (they are positive -> mined 0;
    // concurrent same-value writes are benign)
    if (lds && tid < O) s_m[s_bp[tid]] = 0.0f;

    // 3. FIXUP deltas (wave-0 lanes; proven bit-exact in R9)
    float dll = 0.0f, dpc = 0.0f;
    int dnp = 0;
    if (tid < O) {
        const int o = tid;
        const int p = s_bp[o];
        bool owner = true;
        for (int o2 = o + 1; o2 < O; ++o2)
            if (s_bp[o2] == p) owner = false;  // largest o owns (last-wins scatter)
        if (owner) {
            float4 pr = ((const float4*)priors)[p];
            float cx = pr.x, cy = pr.y, pw = pr.z, ph = pr.w;
            float px0 = cx - pw * 0.5f, py0 = cy - ph * 0.5f;
            float px1 = cx + pw * 0.5f, py1 = cy + ph * 0.5f;
            float pa = (px1 - px0) * (py1 - py0);
            float bto = -1.0f;
            int bti = 0;
            for (int o2 = 0; o2 < O; ++o2) {
                float ov = jac(s_tx0[o2], s_ty0[o2], s_tx1[o2], s_ty1[o2], s_area[o2],
                               px0, py0, px1, py1, pa);
                if (ov > bto) { bto = ov; bti = o2; }
            }
            int c_t = (bto < 0.5f) ? 0 : ((int)s_lab[bti] + 1);
            const float* row = conf + ((size_t)b * P + p) * C;
            float m = row[0];
            for (int j = 1; j < C; ++j) m = fmaxf(m, row[j]);
            float s = 0.0f;
            for (int j = 0; j < C; ++j) s += expf(row[j] - m);
            float lse = m + logf(s);
            int c_n = (int)s_lab[o] + 1;
            float lc_n = lse - row[c_n];
            bool pos_t = c_t > 0;
            float lc_t = lse - row[c_t];
            dpc = lc_n - (pos_t ? lc_t : 0.0f);
            dnp = 1 - (pos_t ? 1 : 0);
            float4 ld = ((const float4*)loc)[(size_t)b * P + p];
            float lv[4] = {ld.x, ld.y, ld.z, ld.w};
            float sl_new = 0.0f, sl_old = 0.0f;
            {
                float mx0 = s_tx0[o], my0 = s_ty0[o], mx1 = s_tx1[o], my1 = s_ty1[o];
                float g[4] = {((mx0 + mx1) * 0.5f - cx) / (0.1f * pw),
                              ((my0 + my1) * 0.5f - cy) / (0.1f * ph),
                              logf(fmaxf((mx1 - mx0) / pw, 1e-8f)) / 0.2f,
                              logf(fmaxf((my1 - my0) / ph, 1e-8f)) / 0.2f};
                for (int q = 0; q < 4; ++q) {
                    float d = lv[q] - g[q];
                    float ad = fabsf(d);
                    sl_new += (ad < 1.0f) ? 0.5f * d * d : (ad - 0.5f);
                }
            }
            if (pos_t) {
                float mx0 = s_tx0[bti], my0 = s_ty0[bti], mx1 = s_tx1[bti], my1 = s_ty1[bti];
                float g[4] = {((mx0 + mx1) * 0.5f - cx) / (0.1f * pw),
                              ((my0 + my1) * 0.5f - cy) / (0.1f * ph),
                              logf(fmaxf((mx1 - mx0) / pw, 1e-8f)) / 0.2f,
                              logf(fmaxf((my1 - my0) / ph, 1e-8f)) / 0.2f};
                for (int q = 0; q < 4; ++q) {
                    float d = lv[q] - g[q];
                    float ad = fabsf(d);
                    sl_old += (ad < 1.0f) ? 0.5f * d * d : (ad - 0.5f);
                }
            }
            dll = sl_new - sl_old;
        }
    }
    if (wv == 0) {
#pragma unroll
        for (int d = 1; d < 64; d <<= 1) {
            dll += __shfl_xor(dll, d, 64);
            dpc += __shfl_xor(dpc, d, 64);
            dnp += __shfl_xor(dnp, d, 64);
        }
        if (lane == 0) { s_fix[0] = dll; s_fix[1] = dpc; s_fixn = dnp; }
    }
    __syncthreads();
    if (tid == 0) {
        float L = 0.f, Pc = 0.f;
        int N = 0;
        for (int w = 0; w < W; ++w) { L += s_wf[w]; Pc += s_wg[w]; N += s_wi[w]; }
        s_bc[0] = L + s_fix[0]; s_bc[1] = Pc + s_fix[1]; s_bn = N + s_fixn;
    }
    __syncthreads();
    const float ll_sum = s_bc[0];
    const float sum_pos = s_bc[1];
    const int npos = s_bn;

    const int k = min(ratio * npos, P - npos);
    if (tid == 0) {
        ll_batch[b] = ll_sum;
        np_batch[b] = npos;
    }

    if (k <= 0) {
        if (tid == 0) lc_batch[b] = sum_pos;
    } else {
        // 4. radix-select on the staged (and forced-zeroed) row
        unsigned prefix = 0u;
        int kr = k;
        for (int pass = 0; pass < 4; ++pass) {
            const int shift = 24 - 8 * pass;
            const unsigned mask = (pass == 0) ? 0u : (0xFFFFFFFFu << (32 - 8 * pass));
            for (int i = tid; i < W * 256; i += TPBS) s_hist[i] = 0;
            __syncthreads();
            for (int i = tid; i < P; i += TPBS) {
                float x;
                if (lds) x = s_m[i];
                else {
                    x = v[i];
                    for (int o = 0; o < O; ++o)
                        if (i == s_bp[o]) x = 0.0f;
                }
                unsigned u = __float_as_uint(x);
                if ((u & mask) == prefix)
                    atomicAdd(&s_hist[wv * 256 + ((u >> shift) & 0xFF)], 1);
            }
            __syncthreads();
            int sge = 0, h = 0;
            if (tid < 256) {
                for (int w = 0; w < W; ++w) h += s_hist[w * 256 + tid];
                int val = h;
#pragma unroll
                for (int d = 1; d < 64; d <<= 1) {
                    int t = __shfl_down(val, d, 64);
                    if (lane + d < 64) val += t;
                }
                if (lane == 0) s_wt[tid >> 6] = val;
                sge = val;
            }
            __syncthreads();
            if (tid < 256) {
                for (int w = (tid >> 6) + 1; w < 4; ++w) sge += s_wt[w];
                int sgt = sge - h;
                if (sge >= kr && sgt < kr) {  // exactly one tid satisfies
                    s_bsel = (unsigned)tid;
                    s_krn = kr - sgt;
                }
            }
            __syncthreads();
            prefix |= s_bsel << shift;
            kr = s_krn;
        }
        const float T = __uint_as_float(prefix);  // exact k-th largest value
        float lsum = 0.0f;
        int lcnt = 0;
        for (int i = tid; i < P; i += TPBS) {
            float x;
            if (lds) x = s_m[i];
            else {
                x = v[i];
                for (int o = 0; o < O; ++o)
                    if (i == s_bp[o]) x = 0.0f;
            }
            if (x > T) { lsum += x; ++lcnt; }
        }
#pragma unroll
        for (int d = 1; d < 64; d <<= 1) {
            lsum += __shfl_xor(lsum, d, 64);
            lcnt += __shfl_xor(lcnt, d, 64);
        }
        if (lane == 0) { s_wf[wv] = lsum; s_wi[wv] = lcnt; }
        __syncthreads();
        if (tid == 0) {
            float S = 0.f;
            int Cn = 0;
            for (int w = 0; w < W; ++w) { S += s_wf[w]; Cn += s_wi[w]; }
            lc_batch[b] = sum_pos + S + (float)(k - Cn) * T;
        }
    }

    // 5. last-block-done finalize (replaces the finalize dispatch)
    __threadfence();  // release our lc/ll/np stores
    if (tid == 0) {
        int old = atomicAdd(counter, 1);  // device-scope
        s_last = (old == B - 1) ? 1 : 0;
    }
    __syncthreads();
    if (s_last) {
        __threadfence();  // acquire other blocks' stores
        float l = 0.0f, c = 0.0f;
        int n = 0;
        for (int i = tid; i < B; i += TPBS) {
            l += ll_batch[i];
            c += lc_batch[i];
            n += np_batch[i];
        }
#pragma unroll
        for (int d = 1; d < 64; d <<= 1) {
            l += __shfl_xor(l, d, 64);
            c += __shfl_xor(c, d, 64);
            n += __shfl_xor(n, d, 64);
        }
        if (lane == 0) { s_wf[wv] = l; s_wg[wv] = c; s_wi[wv] = n; }
        __syncthreads();
        if (tid == 0) {
            float L = 0.f, Cc = 0.f;
            int N = 0;
            for (int w = 0; w < W; ++w) { L += s_wf[w]; Cc += s_wg[w]; N += s_wi[w]; }
            float Nf = (float)N;
            out[0] = L / Nf;
            out[1] = Cc / Nf;
        }
    }
}

extern "C" void kernel_launch(void* const* d_in, const int* in_sizes, int n_in,
                              void* d_out, int out_size, void* d_ws, size_t ws_size,
                              hipStream_t stream) {
    const float* loc = (const float*)d_in[0];
    const float* conf = (const float*)d_in[1];
    const float* priors = (const float*)d_in[2];
    const float* targets = (const float*)d_in[3];

    const int P = in_sizes[2] / 4;
    const int B = in_sizes[0] / (P * 4);
    const int C = in_sizes[1] / (in_sizes[0] / 4);  // conf / (B*P)
    const int O = in_sizes[3] / (B * 5);
    const size_t BP = (size_t)B * P;
    const int CB2 = (P + TPB - 1) / TPB;   // chunks per batch

    // ws layout (8B-aligned first; everything fully written before read):
    ull* pkeys = (ull*)d_ws;                                // B*O*CB2 u64
    float* mined = (float*)(pkeys + (size_t)B * O * CB2);   // BP f32
    float* part_ll = mined + BP;                            // B*CB2 f32
    float* part_pc = part_ll + (size_t)B * CB2;             // B*CB2 f32
    int* part_np = (int*)(part_pc + (size_t)B * CB2);       // B*CB2 i32
    float* ll_batch = (float*)(part_np + (size_t)B * CB2);  // B f32
    float* lc_batch = ll_batch + B;                         // B f32
    int* np_batch = (int*)(lc_batch + B);                   // B i32
    int* counter = np_batch + B;                            // 1 i32 (init by fused_kernel)

    if (O == 8 && C == 21) {
        fused_kernel<8, 21><<<B * CB2, TPB, 0, stream>>>(
            loc, priors, targets, conf, P, O, C, CB2,
            mined, pkeys, part_ll, part_pc, part_np, counter);
        select_kernel<8, 21><<<B, TPBS, 0, stream>>>(
            mined, conf, loc, priors, targets, pkeys, part_ll, part_pc, part_np,
            ll_batch, lc_batch, np_batch, P, O, C, CB2, 3, B, counter, (float*)d_out);
    } else {
        fused_kernel<0, 0><<<B * CB2, TPB, 0, stream>>>(
            loc, priors, targets, conf, P, O, C, CB2,
            mined, pkeys, part_ll, part_pc, part_np, counter);
        select_kernel<0, 0><<<B, TPBS, 0, stream>>>(
            mined, conf, loc, priors, targets, pkeys, part_ll, part_pc, part_np,
            ll_batch, lc_batch, np_batch, P, O, C, CB2, 3, B, counter, (float*)d_out);
    }
}

// Round 12
// 125.007 us; speedup vs baseline: 1.1426x; 1.1426x over previous
//
#include <hip/hip_runtime.h>
#include <math.h>

#define TPB 256
#define TPBS 1024    // select block size
#define LDSF 12288   // select LDS stage capacity in floats (48 KB)

typedef unsigned long long ull;
typedef float pf4 __attribute__((ext_vector_type(4), aligned(4)));  // 4B-aligned float4

__device__ __forceinline__ float jac(float tx0, float ty0, float tx1, float ty1, float ta,
                                     float px0, float py0, float px1, float py1, float pa) {
    float ltx = fmaxf(tx0, px0), lty = fmaxf(ty0, py0);
    float rbx = fminf(tx1, px1), rby = fminf(ty1, py1);
    float w = fmaxf(rbx - ltx, 0.0f), h = fmaxf(rby - lty, 0.0f);
    float inter = w * h;
    return inter / (ta + pa - inter);
}

// ONE pass over all priors (grid B*CB2, thread-per-prior), producing:
//  - per-chunk per-o best-prior key partials (match1 folded in: jac computed
//    ONCE for both the per-o argmax and the per-p sweep)
//  - TENTATIVE mined / smooth-L1 / positive sums (no forced-match override —
//    that touches <= O priors per batch; fixed up in select, proven bit-exact
//    absmax 0.0 in R9/R11)
// Key = (ov_bits<<32) | (0xFFFFFFFF - p): ov >= 0 -> bit-monotone; ~p gives
// first-max (smallest p) on ties, matching the reference argmax over P.
template <int ON, int CN>
__global__ __launch_bounds__(TPB) void fused_kernel(
    const float* __restrict__ loc, const float* __restrict__ priors,
    const float* __restrict__ targets, const float* __restrict__ conf,
    int P, int O_rt, int C_rt, int CB2,
    float* __restrict__ mined, ull* __restrict__ pkeys,
    float* __restrict__ part_ll, float* __restrict__ part_pc,
    int* __restrict__ part_np) {
    constexpr int OMAX = (ON > 0) ? ON : 64;
    constexpr int CC = (CN > 0) ? CN : 32;
    const int O = (ON > 0) ? ON : O_rt;
    const int C = (CN > 0) ? CN : C_rt;
    const int b = blockIdx.x / CB2;
    const int chunk = blockIdx.x % CB2;
    const int tid = threadIdx.x;
    const int p = chunk * TPB + tid;
    const bool pv = (p < P);
    const int lane = tid & 63, wv = tid >> 6;

    __shared__ float s_tx0[OMAX], s_ty0[OMAX], s_tx1[OMAX], s_ty1[OMAX];
    __shared__ float s_lab[OMAX], s_area[OMAX];
    __shared__ ull s_wk[TPB / 64][OMAX];
    __shared__ float s_wll[TPB / 64], s_wpc[TPB / 64];
    __shared__ int s_wnp[TPB / 64];

    // ---- issue conf-row + prior loads FIRST (latency overlaps setup) ----
    float rv[CC];
    float4 pr4 = make_float4(0.f, 0.f, 1.f, 1.f);
    if (pv) {
        const float* row = conf + ((size_t)b * P + p) * C;
        if (CN > 0) {
#pragma unroll
            for (int q = 0; q < CN / 4; ++q) {
                pf4 v = *(const pf4*)(row + 4 * q);
#pragma unroll
                for (int e = 0; e < 4; ++e) rv[4 * q + e] = v[e];
            }
#pragma unroll
            for (int j = (CN / 4) * 4; j < CN; ++j) rv[j] = row[j];
        } else {
            for (int j = 0; j < C; ++j) rv[j] = row[j];
        }
        pr4 = ((const float4*)priors)[p];
    }

    for (int o = tid; o < O; o += TPB) {
        const float* t = targets + ((size_t)b * O + o) * 5;
        float x0 = t[0], y0 = t[1], x1 = t[2], y1 = t[3];
        s_tx0[o] = x0; s_ty0[o] = y0; s_tx1[o] = x1; s_ty1[o] = y1;
        s_lab[o] = t[4];
        s_area[o] = (x1 - x0) * (y1 - y0);
    }
    __syncthreads();

    // ---- jac sweep: tentative per-p best (first-max over o) AND per-o
    //      wave-reduced argmax key (reduced inline, register-light) ----
    float cx = pr4.x, cy = pr4.y, pw = pr4.z, ph = pr4.w;
    float px0 = cx - pw * 0.5f, py0 = cy - ph * 0.5f;
    float px1 = cx + pw * 0.5f, py1 = cy + ph * 0.5f;
    float pa = (px1 - px0) * (py1 - py0);
    float bto = -1.0f;
    int bti = 0;
    for (int o = 0; o < O; ++o) {
        ull kk = 0ull;
        if (pv) {
            float ov = jac(s_tx0[o], s_ty0[o], s_tx1[o], s_ty1[o], s_area[o],
                           px0, py0, px1, py1, pa);
            kk = ((ull)__float_as_uint(ov) << 32) |
                 (ull)(0xFFFFFFFFu - (unsigned)p);
            if (ov > bto) { bto = ov; bti = o; }  // strictly > keeps earliest o
        }
#pragma unroll
        for (int d = 1; d < 64; d <<= 1) {
            ull other = __shfl_xor(kk, d, 64);
            if (other > kk) kk = other;
        }
        if (lane == 0) s_wk[wv][o] = kk;
    }
    __syncthreads();
    if (tid < O) {
        ull kk = s_wk[0][tid];
        for (int w = 1; w < TPB / 64; ++w)
            if (s_wk[w][tid] > kk) kk = s_wk[w][tid];
        pkeys[((size_t)b * O + tid) * CB2 + chunk] = kk;
    }

    // ---- tentative conf loss + smooth-L1 (no forced override) ----
    float ll = 0.0f, pc = 0.0f;
    int np = 0;
    if (pv) {
        float m = rv[0];
#pragma unroll
        for (int j = 1; j < CC; ++j) { if (CN > 0 || j < C) m = fmaxf(m, rv[j]); }
        float s = 0.0f;
#pragma unroll
        for (int j = 0; j < CC; ++j) { if (CN > 0 || j < C) s += expf(rv[j] - m); }
        float lse = m + logf(s);

        int c = (bto < 0.5f) ? 0 : ((int)s_lab[bti] + 1);
        float rowc = rv[0];
#pragma unroll
        for (int j = 1; j < CC; ++j) { if (CN > 0 || j < C) { if (c == j) rowc = rv[j]; } }
        float lc = lse - rowc;  // >= 0 always (s >= 1)

        bool pos = c > 0;
        mined[(size_t)b * P + p] = pos ? 0.0f : lc;
        if (pos) {
            pc = lc;
            np = 1;
            float mx0 = s_tx0[bti], my0 = s_ty0[bti];
            float mx1 = s_tx1[bti], my1 = s_ty1[bti];
            float g0 = ((mx0 + mx1) * 0.5f - cx) / (0.1f * pw);
            float g1 = ((my0 + my1) * 0.5f - cy) / (0.1f * ph);
            float g2 = logf(fmaxf((mx1 - mx0) / pw, 1e-8f)) / 0.2f;
            float g3 = logf(fmaxf((my1 - my0) / ph, 1e-8f)) / 0.2f;
            float4 ld = ((const float4*)loc)[(size_t)b * P + p];
            float gt4[4] = {g0, g1, g2, g3};
            float lv[4] = {ld.x, ld.y, ld.z, ld.w};
#pragma unroll
            for (int q = 0; q < 4; ++q) {
                float d = lv[q] - gt4[q];
                float ad = fabsf(d);
                ll += (ad < 1.0f) ? 0.5f * d * d : (ad - 0.5f);
            }
        }
    }

#pragma unroll
    for (int d = 1; d < 64; d <<= 1) {
        ll += __shfl_xor(ll, d, 64);
        pc += __shfl_xor(pc, d, 64);
        np += __shfl_xor(np, d, 64);
    }
    if (lane == 0) { s_wll[wv] = ll; s_wpc[wv] = pc; s_wnp[wv] = np; }
    __syncthreads();
    if (tid == 0) {
        float L = 0.f, Pc = 0.f;
        int N = 0;
        for (int w = 0; w < TPB / 64; ++w) { L += s_wll[w]; Pc += s_wpc[w]; N += s_wnp[w]; }
        part_ll[blockIdx.x] = L;
        part_pc[blockIdx.x] = Pc;
        part_np[blockIdx.x] = N;
    }
}

// One 1024-thread block per batch. NO __threadfence / device counter (the
// R11 43-us constant stall): per-batch results are plain stores; a separate
// tiny finalize dispatch does the last 64-element reduction.
//  1. stage mined row into static LDS (coalesced; not scratch)
//  2. reduce per-chunk argmax keys -> bp[o]; zero forced priors in s_m
//  3. FIXUP (wave 0, <= O priors; dedup: largest o owns p = last-wins
//     scatter): recompute tentative contribution bit-identically, apply delta
//  4. radix-select k-th largest (values >= 0, bit-monotone); per-wave LDS
//     histograms + intra-wave shuffle suffix scan;
//     sum(top-k) = sum_{>T} + (k-cnt_gt)*T — exact under ties
template <int ON, int CN>
__global__ __launch_bounds__(TPBS) void select_kernel(
    const float* __restrict__ mined, const float* __restrict__ conf,
    const float* __restrict__ loc, const float* __restrict__ priors,
    const float* __restrict__ targets, const ull* __restrict__ pkeys,
    const float* __restrict__ part_ll, const float* __restrict__ part_pc,
    const int* __restrict__ part_np,
    float* __restrict__ ll_batch, float* __restrict__ lc_batch,
    int* __restrict__ np_batch,
    int P, int O_rt, int C_rt, int CB2, int ratio) {
    constexpr int OMAX = (ON > 0) ? ON : 64;
    const int O = (ON > 0) ? ON : O_rt;
    const int C = (CN > 0) ? CN : C_rt;
    const int b = blockIdx.x, tid = threadIdx.x;
    const int lane = tid & 63, wv = tid >> 6;
    constexpr int W = TPBS / 64;  // 16 waves
    const float* v = mined + (size_t)b * P;
    const bool lds = (P <= LDSF);

    __shared__ float s_m[LDSF];       // 48 KB staged row
    __shared__ int s_hist[W * 256];   // 16 KB per-wave histograms
    __shared__ float s_tx0[OMAX], s_ty0[OMAX], s_tx1[OMAX], s_ty1[OMAX];
    __shared__ float s_lab[OMAX], s_area[OMAX];
    __shared__ ull s_keys[OMAX];
    __shared__ int s_bp[OMAX];
    __shared__ float s_wf[W], s_wg[W];
    __shared__ int s_wi[W];
    __shared__ int s_wt[4];
    __shared__ unsigned s_bsel;
    __shared__ int s_krn;
    __shared__ float s_bc[2], s_fix[2];
    __shared__ int s_bn, s_fixn;

    // 1. stage mined row; overlap: per-chunk tentative partial reduction
    if (lds) {
        for (int i = tid; i < P; i += TPBS) s_m[i] = v[i];
    }
    float pll = 0.0f, ppc = 0.0f;
    int pnp = 0;
    for (int i = tid; i < CB2; i += TPBS) {
        pll += part_ll[b * CB2 + i];
        ppc += part_pc[b * CB2 + i];
        pnp += part_np[b * CB2 + i];
    }
#pragma unroll
    for (int d = 1; d < 64; d <<= 1) {
        pll += __shfl_xor(pll, d, 64);
        ppc += __shfl_xor(ppc, d, 64);
        pnp += __shfl_xor(pnp, d, 64);
    }
    if (lane == 0) { s_wf[wv] = pll; s_wg[wv] = ppc; s_wi[wv] = pnp; }

    if (tid < O) {
        const float* t = targets + ((size_t)b * O + tid) * 5;
        float x0 = t[0], y0 = t[1], x1 = t[2], y1 = t[3];
        s_tx0[tid] = x0; s_ty0[tid] = y0; s_tx1[tid] = x1; s_ty1[tid] = y1;
        s_lab[tid] = t[4];
        s_area[tid] = (x1 - x0) * (y1 - y0);
        s_keys[tid] = 0ull;
    }
    __syncthreads();

    // 2. reduce per-chunk keys (block-local LDS atomics, O*CB2 entries)
    for (int i = tid; i < O * CB2; i += TPBS) {
        int o = i / CB2, s = i % CB2;
        atomicMax(&s_keys[o], pkeys[((size_t)b * O + o) * CB2 + s]);
    }
    __syncthreads();
    if (tid < O)
        s_bp[tid] = (int)(0xFFFFFFFFu - (unsigned)(s_keys[tid] & 0xFFFFFFFFull));
    __syncthreads();

    // zero forced priors in the staged row (they are positive -> mined 0;
    // concurrent same-value writes are benign)
    if (lds && tid < O) s_m[s_bp[tid]] = 0.0f;

    // 3. FIXUP deltas (wave-0 lanes; proven bit-exact in R9/R11)
    float dll = 0.0f, dpc = 0.0f;
    int dnp = 0;
    if (tid < O) {
        const int o = tid;
        const int p = s_bp[o];
        bool owner = true;
        for (int o2 = o + 1; o2 < O; ++o2)
            if (s_bp[o2] == p) owner = false;  // largest o owns (last-wins scatter)
        if (owner) {
            float4 pr = ((const float4*)priors)[p];
            float cx = pr.x, cy = pr.y, pw = pr.z, ph = pr.w;
            float px0 = cx - pw * 0.5f, py0 = cy - ph * 0.5f;
            float px1 = cx + pw * 0.5f, py1 = cy + ph * 0.5f;
            float pa = (px1 - px0) * (py1 - py0);
            float bto = -1.0f;
            int bti = 0;
            for (int o2 = 0; o2 < O; ++o2) {
                float ov = jac(s_tx0[o2], s_ty0[o2], s_tx1[o2], s_ty1[o2], s_area[o2],
                               px0, py0, px1, py1, pa);
                if (ov > bto) { bto = ov; bti = o2; }
            }
            int c_t = (bto < 0.5f) ? 0 : ((int)s_lab[bti] + 1);
            const float* row = conf + ((size_t)b * P + p) * C;
            float m = row[0];
            for (int j = 1; j < C; ++j) m = fmaxf(m, row[j]);
            float s = 0.0f;
            for (int j = 0; j < C; ++j) s += expf(row[j] - m);
            float lse = m + logf(s);
            int c_n = (int)s_lab[o] + 1;
            float lc_n = lse - row[c_n];
            bool pos_t = c_t > 0;
            float lc_t = lse - row[c_t];
            dpc = lc_n - (pos_t ? lc_t : 0.0f);
            dnp = 1 - (pos_t ? 1 : 0);
            float4 ld = ((const float4*)loc)[(size_t)b * P + p];
            float lv[4] = {ld.x, ld.y, ld.z, ld.w};
            float sl_new = 0.0f, sl_old = 0.0f;
            {
                float mx0 = s_tx0[o], my0 = s_ty0[o], mx1 = s_tx1[o], my1 = s_ty1[o];
                float g[4] = {((mx0 + mx1) * 0.5f - cx) / (0.1f * pw),
                              ((my0 + my1) * 0.5f - cy) / (0.1f * ph),
                              logf(fmaxf((mx1 - mx0) / pw, 1e-8f)) / 0.2f,
                              logf(fmaxf((my1 - my0) / ph, 1e-8f)) / 0.2f};
                for (int q = 0; q < 4; ++q) {
                    float d = lv[q] - g[q];
                    float ad = fabsf(d);
                    sl_new += (ad < 1.0f) ? 0.5f * d * d : (ad - 0.5f);
                }
            }
            if (pos_t) {
                float mx0 = s_tx0[bti], my0 = s_ty0[bti], mx1 = s_tx1[bti], my1 = s_ty1[bti];
                float g[4] = {((mx0 + mx1) * 0.5f - cx) / (0.1f * pw),
                              ((my0 + my1) * 0.5f - cy) / (0.1f * ph),
                              logf(fmaxf((mx1 - mx0) / pw, 1e-8f)) / 0.2f,
                              logf(fmaxf((my1 - my0) / ph, 1e-8f)) / 0.2f};
                for (int q = 0; q < 4; ++q) {
                    float d = lv[q] - g[q];
                    float ad = fabsf(d);
                    sl_old += (ad < 1.0f) ? 0.5f * d * d : (ad - 0.5f);
                }
            }
            dll = sl_new - sl_old;
        }
    }
    if (wv == 0) {
#pragma unroll
        for (int d = 1; d < 64; d <<= 1) {
            dll += __shfl_xor(dll, d, 64);
            dpc += __shfl_xor(dpc, d, 64);
            dnp += __shfl_xor(dnp, d, 64);
        }
        if (lane == 0) { s_fix[0] = dll; s_fix[1] = dpc; s_fixn = dnp; }
    }
    __syncthreads();
    if (tid == 0) {
        float L = 0.f, Pc = 0.f;
        int N = 0;
        for (int w = 0; w < W; ++w) { L += s_wf[w]; Pc += s_wg[w]; N += s_wi[w]; }
        s_bc[0] = L + s_fix[0]; s_bc[1] = Pc + s_fix[1]; s_bn = N + s_fixn;
    }
    __syncthreads();
    const float ll_sum = s_bc[0];
    const float sum_pos = s_bc[1];
    const int npos = s_bn;

    const int k = min(ratio * npos, P - npos);
    if (tid == 0) {
        ll_batch[b] = ll_sum;
        np_batch[b] = npos;
    }
    if (k <= 0) {
        if (tid == 0) lc_batch[b] = sum_pos;
        return;
    }

    // 4. radix-select on the staged (and forced-zeroed) row
    unsigned prefix = 0u;
    int kr = k;
    for (int pass = 0; pass < 4; ++pass) {
        const int shift = 24 - 8 * pass;
        const unsigned mask = (pass == 0) ? 0u : (0xFFFFFFFFu << (32 - 8 * pass));
        for (int i = tid; i < W * 256; i += TPBS) s_hist[i] = 0;
        __syncthreads();
        for (int i = tid; i < P; i += TPBS) {
            float x;
            if (lds) x = s_m[i];
            else {
                x = v[i];
                for (int o = 0; o < O; ++o)
                    if (i == s_bp[o]) x = 0.0f;
            }
            unsigned u = __float_as_uint(x);
            if ((u & mask) == prefix)
                atomicAdd(&s_hist[wv * 256 + ((u >> shift) & 0xFF)], 1);
        }
        __syncthreads();
        int sge = 0, h = 0;
        if (tid < 256) {
            for (int w = 0; w < W; ++w) h += s_hist[w * 256 + tid];
            int val = h;
#pragma unroll
            for (int d = 1; d < 64; d <<= 1) {
                int t = __shfl_down(val, d, 64);
                if (lane + d < 64) val += t;
            }
            if (lane == 0) s_wt[tid >> 6] = val;
            sge = val;
        }
        __syncthreads();
        if (tid < 256) {
            for (int w = (tid >> 6) + 1; w < 4; ++w) sge += s_wt[w];
            int sgt = sge - h;
            if (sge >= kr && sgt < kr) {  // exactly one tid satisfies
                s_bsel = (unsigned)tid;
                s_krn = kr - sgt;
            }
        }
        __syncthreads();
        prefix |= s_bsel << shift;
        kr = s_krn;
        // no trailing barrier: s_bsel/s_krn next written only after two
        // barriers of the following pass
    }
    const float T = __uint_as_float(prefix);  // exact k-th largest value
    float lsum = 0.0f;
    int lcnt = 0;
    for (int i = tid; i < P; i += TPBS) {
        float x;
        if (lds) x = s_m[i];
        else {
            x = v[i];
            for (int o = 0; o < O; ++o)
                if (i == s_bp[o]) x = 0.0f;
        }
        if (x > T) { lsum += x; ++lcnt; }
    }
#pragma unroll
    for (int d = 1; d < 64; d <<= 1) {
        lsum += __shfl_xor(lsum, d, 64);
        lcnt += __shfl_xor(lcnt, d, 64);
    }
    if (lane == 0) { s_wf[wv] = lsum; s_wi[wv] = lcnt; }
    __syncthreads();
    if (tid == 0) {
        float S = 0.f;
        int Cn = 0;
        for (int w = 0; w < W; ++w) { S += s_wf[w]; Cn += s_wi[w]; }
        lc_batch[b] = sum_pos + S + (float)(k - Cn) * T;
    }
}

__global__ __launch_bounds__(TPB) void finalize_kernel(
    const float* __restrict__ ll_batch, const int* __restrict__ np_batch,
    const float* __restrict__ lc_batch, int B, float* __restrict__ out) {
    const int tid = threadIdx.x;
    __shared__ float s_l[TPB], s_c[TPB];
    __shared__ int s_n[TPB];
    float l = 0.0f, c = 0.0f;
    int n = 0;
    for (int i = tid; i < B; i += TPB) {
        l += ll_batch[i];
        c += lc_batch[i];
        n += np_batch[i];
    }
    s_l[tid] = l; s_c[tid] = c; s_n[tid] = n;
    __syncthreads();
    for (int s = TPB / 2; s > 0; s >>= 1) {
        if (tid < s) {
            s_l[tid] += s_l[tid + s];
            s_c[tid] += s_c[tid + s];
            s_n[tid] += s_n[tid + s];
        }
        __syncthreads();
    }
    if (tid == 0) {
        float N = (float)s_n[0];
        out[0] = s_l[0] / N;
        out[1] = s_c[0] / N;
    }
}

extern "C" void kernel_launch(void* const* d_in, const int* in_sizes, int n_in,
                              void* d_out, int out_size, void* d_ws, size_t ws_size,
                              hipStream_t stream) {
    const float* loc = (const float*)d_in[0];
    const float* conf = (const float*)d_in[1];
    const float* priors = (const float*)d_in[2];
    const float* targets = (const float*)d_in[3];

    const int P = in_sizes[2] / 4;
    const int B = in_sizes[0] / (P * 4);
    const int C = in_sizes[1] / (in_sizes[0] / 4);  // conf / (B*P)
    const int O = in_sizes[3] / (B * 5);
    const size_t BP = (size_t)B * P;
    const int CB2 = (P + TPB - 1) / TPB;   // chunks per batch

    // ws layout (8B-aligned first; everything fully written before read):
    ull* pkeys = (ull*)d_ws;                                // B*O*CB2 u64
    float* mined = (float*)(pkeys + (size_t)B * O * CB2);   // BP f32
    float* part_ll = mined + BP;                            // B*CB2 f32
    float* part_pc = part_ll + (size_t)B * CB2;             // B*CB2 f32
    int* part_np = (int*)(part_pc + (size_t)B * CB2);       // B*CB2 i32
    float* ll_batch = (float*)(part_np + (size_t)B * CB2);  // B f32
    float* lc_batch = ll_batch + B;                         // B f32
    int* np_batch = (int*)(lc_batch + B);                   // B i32

    if (O == 8 && C == 21) {
        fused_kernel<8, 21><<<B * CB2, TPB, 0, stream>>>(
            loc, priors, targets, conf, P, O, C, CB2,
            mined, pkeys, part_ll, part_pc, part_np);
        select_kernel<8, 21><<<B, TPBS, 0, stream>>>(
            mined, conf, loc, priors, targets, pkeys, part_ll, part_pc, part_np,
            ll_batch, lc_batch, np_batch, P, O, C, CB2, 3);
    } else {
        fused_kernel<0, 0><<<B * CB2, TPB, 0, stream>>>(
            loc, priors, targets, conf, P, O, C, CB2,
            mined, pkeys, part_ll, part_pc, part_np);
        select_kernel<0, 0><<<B, TPBS, 0, stream>>>(
            mined, conf, loc, priors, targets, pkeys, part_ll, part_pc, part_np,
            ll_batch, lc_batch, np_batch, P, O, C, CB2, 3);
    }

    finalize_kernel<<<1, TPB, 0, stream>>>(ll_batch, np_batch, lc_batch, B,
                                           (float*)d_out);
}